// Round 8
// baseline (494.438 us; speedup 1.0000x reference)
//
#include <hip/hip_runtime.h>
#include <hip/hip_bf16.h>

// Packed varlen causal GQA attention (flash-style), MI355X gfx950.
// Q [T,H,D] f32, K/V [T,G,D] f32, cu_seqlens [9] int32 -> O [T,H,D] f32.
// T=4096, H=16, G=4, D=128, SCALE=1/sqrt(128).
//
// R16 = R15 (persistent queue + bf16 K/V pre-conversion, fwd 72us) +
//  1. UNIFORM SMALL ITEMS: nc = min(8, ceil(nblk/12)), even chunk ->
//     max item ~6-8 iters (was ~11), ~750 items for 512 workers. R13's
//     regression drivers fixed: partials stored BF16 (32KB/slot, so
//     total partial bytes ~unchanged despite 2x slots) and merge is
//     inline + L3-hot (no extra HBM round-trip dispatch).
//  2. INLINE MERGE (split-K semaphore): last-finishing chunk of a
//     (tile,g) merges all partials with all 512 threads. Release =
//     per-thread __threadfence + __syncthreads + device atomicAdd;
//     acquire = __threadfence after observing count==nc-1 (G16).
//  3. AUX PIPELINE FUSED: prep converts K + transposes V only (Qbf
//     dropped -- Q has ~2x reuse, converted in-body as verified R12);
//     build_queue + counter-zero folded into prep. 2 dispatches total.
//     R15 spent ~45us in aux dispatches vs 72us fwd.
// R14 lessons kept: no shfl P-reshuffle, staging writes after barrier.
//
// Per item: 512 threads = 8 waves; waves 0-3 (split 0) handle heads
// g*4+0..3 over the first half of the chunk's key range; waves 4-7
// (split 1) the second half. Independent (m,l,O) per split, merged via
// LDS; merged max committed back into m_run (R10 fix) so stored partials
// (m,l,O) share one reference max. Defer-rescale: skip oacc*=alpha when
// no lane's max grew (exact). Mask fast-path on interior iterations.
// MFMA layouts (HW-verified m89/m91/m118-m122), 16x16x32_bf16:
//   A[m=lane&15][k=quad*8+j], B[k=quad*8+j][n=lane&15],
//   C/D: row m = quad*4+reg, col n = lane&15.

#define T_TOK 4096
#define NH    16
#define NG    4
#define HD    128
#define NCU   9
#define NTILE 128

// Workspace layout (float-element offsets):
//   O_part bf16 [tile128][g4][chunk8][hw4][q32][d128]  = 33,554,432 f-slots
//   ml  f32   [tile][g][chunk8][row128][{m,l}]         =  1,048,576 f
//   queue (ints): [0]=total,[1]=pop,[2..4097]=entries  =      4,100 f
//   counters [tile][g] int                             =        512 f
//   Kbf [t][g][d] bf16                                 =  1,048,576 f
//   Vtb [g][d][t] bf16 (pre-transposed)                =  1,048,576 f
#define ML_OFF  33554432l
#define Q_OFF   34603008l
#define CNT_OFF 34607108l
#define KBF_OFF 34607620l
#define VTB_OFF 35656196l
#define WS_END  36704772l

typedef short          short8_t __attribute__((ext_vector_type(8)));
typedef float          float4_t __attribute__((ext_vector_type(4)));
typedef unsigned int   uint2_t  __attribute__((ext_vector_type(2)));
typedef unsigned short ushort;

static __device__ inline unsigned pack2(float a, float b) {
    __hip_bfloat162 h = __float22bfloat162_rn(make_float2(a, b));
    union { __hip_bfloat162 h; unsigned u; } c; c.h = h;
    return c.u;
}
static __device__ inline short8_t cvt8(float4_t lo, float4_t hi) {
    union { unsigned u[4]; short8_t s; } r;
    r.u[0] = pack2(lo[0], lo[1]); r.u[1] = pack2(lo[2], lo[3]);
    r.u[2] = pack2(hi[0], hi[1]); r.u[3] = pack2(hi[2], hi[3]);
    return r.s;
}
static __device__ inline float bf2f(ushort u) {
    union { unsigned i; float f; } c; c.i = ((unsigned)u) << 16; return c.f;
}
// chunk count: target ~12 kblocks/chunk, cap 8 (WS slot dim)
static __device__ __forceinline__ int nc_of(int nblk) {
    int nc = (nblk + 11) / 12;
    return nc < 1 ? 1 : (nc > 8 ? 8 : nc);
}

// ---- prep: K f32->bf16, V f32->bf16 transposed [g][d][t], build queue ----
#define NPK 1048576l   // K bf16 pairs
__global__ __launch_bounds__(256) void prep_all(
    const float* __restrict__ K, const float* __restrict__ V,
    const int* __restrict__ cu, float* __restrict__ WS)
{
    const int b = (int)blockIdx.x, tid = (int)threadIdx.x;
    if (b < 512) {
        // K convert (flat pairs)
        unsigned* Kb = (unsigned*)(WS + KBF_OFF);
        for (long p = (long)b * 256 + tid; p < NPK; p += 512l * 256) {
            const float2 v = *(const float2*)&K[2 * p];
            Kb[p] = pack2(v.x, v.y);
        }
    } else if (b < 1536) {
        // V transpose: tile 64 t x 32 d per block, via LDS (R15-verified)
        ushort* Vtb = (ushort*)(WS + VTB_OFF);
        const int bt  = b - 512;             // 0..1023
        const int g   = bt >> 8;             // 4
        const int rem = bt & 255;            // 4 d-tiles x 64 t-tiles
        const int d0  = (rem >> 6) * 32;
        const int t0  = (rem & 63) * 64;
        __shared__ ushort tile[64][36];
        const int i2 = tid >> 3, jl = (tid & 7) * 4;
        #pragma unroll
        for (int ii = 0; ii < 2; ++ii) {
            const int t = t0 + i2 + ii * 32;
            const float4_t v = *(const float4_t*)&V[((long)t * NG + g) * HD + d0 + jl];
            *(unsigned*)&tile[i2 + ii * 32][jl]     = pack2(v[0], v[1]);
            *(unsigned*)&tile[i2 + ii * 32][jl + 2] = pack2(v[2], v[3]);
        }
        __syncthreads();
        const int jj = tid >> 3, tl = (tid & 7) * 8;
        union { ushort s[8]; short8_t v; } o;
        #pragma unroll
        for (int r = 0; r < 8; ++r) o.s[r] = tile[tl + r][jj];
        *(short8_t*)&Vtb[((long)(g * HD + d0 + jj)) * T_TOK + t0 + tl] = o.v;
    } else {
        // build queue (heaviest tiles first) + zero merge counters
        int* qwork = (int*)(WS + Q_OFF);
        int* cnt   = (int*)(WS + CNT_OFF);
        __shared__ int nblk_s[NTILE];
        __shared__ int sortedE[NTILE + 1];
        if (tid >= 128) {
            for (int i = tid - 128; i < 512; i += 128) cnt[i] = 0;
            return;
        }
        const int t = tid;                   // tile id 0..127
        const int qbase = t * 32;
        int seg0 = 0;
        #pragma unroll
        for (int j = 1; j < NCU; ++j) { int cj = cu[j]; if (cj <= qbase) seg0 = cj; }
        const int k0   = seg0 & ~31;
        const int nblk = (qbase + 32 - k0) >> 5;   // 1..128
        nblk_s[t] = nblk;
        __syncthreads();
        // rank by (nblk desc, tile asc) -- strict total order
        int r = 0;
        for (int j = 0; j < NTILE; ++j) {
            int nj = nblk_s[j];
            if (nj > nblk || (nj == nblk && j < t)) ++r;
        }
        const int nc = nc_of(nblk);
        sortedE[r] = 4 * nc;
        __syncthreads();
        if (t == 0) {
            int s = 0;
            for (int j = 0; j < NTILE; ++j) { int v = sortedE[j]; sortedE[j] = s; s += v; }
            sortedE[NTILE] = s;
            qwork[0] = s;
            qwork[1] = 0;
        }
        __syncthreads();
        int off = 2 + sortedE[r];
        for (int g = 0; g < NG; ++g)
            for (int cz = 0; cz < nc; ++cz)
                qwork[off++] = (t << 5) | (g << 3) | cz;   // tile:7|g:2|cz:3
    }
}

// ---- tile body. CHB: false = mono f32 direct, true = chunked bf16 ----
template <bool CHB>
static __device__ __forceinline__ void attn_tile_body(
    const float* __restrict__ Q, const float* __restrict__ K,
    const float* __restrict__ V,
    const ushort* __restrict__ Kb, const ushort* __restrict__ Vtb,
    const int* __restrict__ cu,
    float* __restrict__ O, float* __restrict__ WS,
    unsigned char* smem, int qtile, int g, int cz)
{
    ushort (*Ks)[32][136]   = (ushort (*)[32][136])smem;
    ushort (*Vt)[128][40]   = (ushort (*)[128][40])(smem + 17408);
    ushort (*pb)[2][16][40] = (ushort (*)[2][16][40])(smem + 37888);

    const int tid   = threadIdx.x;
    const int wave  = tid >> 6;          // 0..7
    const int split = wave >> 2;         // 0..1 (key-range half)
    const int hw    = wave & 3;
    const int lane  = tid & 63;
    const int h     = g * 4 + hw;        // query head; h//4 == g (jnp.repeat)
    const int col   = lane & 15;
    const int quad  = lane >> 4;

    const int qbase = qtile * 32;        // 32 q rows per block
    const int qq[2] = { qbase + col, qbase + 16 + col };

    // segment starts: per-lane per-tile, and block-uniform for k0
    int seg_start[2] = {0, 0}, seg0 = 0;
    #pragma unroll
    for (int j = 1; j < NCU; ++j) {
        int cj = cu[j];
        if (cj <= qq[0])  seg_start[0] = cj;
        if (cj <= qq[1])  seg_start[1] = cj;
        if (cj <= qbase)  seg0         = cj;
    }
    const int k0       = seg0 & ~31;
    const int nblk_tot = (qbase + 32 - k0) >> 5;      // 32-key blocks in span

    int nc = 1, kb_lo = 0, nblk = nblk_tot;
    if (CHB) {
        nc = nc_of(nblk_tot);
        int chunk = ((nblk_tot + nc - 1) / nc + 1) & ~1;  // EVEN: split never
                                                          // overhangs next chunk
        kb_lo = cz * chunk;
        nblk  = nblk_tot - kb_lo;
        if (nblk > chunk) nblk = chunk;
        if (nblk < 1) return;                             // defensive (unreached)
    }
    const int nb0    = (nblk + 1) >> 1;               // iterations per split
    const int kstart = k0 + (kb_lo + split * nb0) * 32;

    // wave-uniform max seg_start per q-tile (seg_start monotone in col)
    const int smax[2] = { __shfl(seg_start[0], 15), __shfl(seg_start[1], 15) };

    // Q fragments (B-operand of S^T = K*Q^T), 2 tiles. dim = c*32+quad*8+j.
    short8_t qf[2][4];
    #pragma unroll
    for (int tt = 0; tt < 2; ++tt) {
        const float* qp = Q + ((long)qq[tt] * NH + h) * HD + quad * 8;
        #pragma unroll
        for (int c = 0; c < 4; ++c)
            qf[tt][c] = cvt8(*(const float4_t*)(qp + c * 32),
                             *(const float4_t*)(qp + c * 32 + 4));
    }

    float4_t oacc[2][8];
    #pragma unroll
    for (int tt = 0; tt < 2; ++tt)
        #pragma unroll
        for (int dt = 0; dt < 8; ++dt) oacc[tt][dt] = (float4_t){0.f, 0.f, 0.f, 0.f};

    float m_run[2] = {-10000.0f, -10000.0f};
    float l_run[2] = {0.0f, 0.0f};
    const float c_scale = 0.08838834764831845f * 1.4426950408889634f; // SCALE*log2e

    // staging thread mapping (256 threads per split, 32 keys x 128 dims)
    const int stid = tid & 255;
    const int ki  = stid >> 3;           // K: key-in-tile
    const int ch  = (stid & 7) * 16;     // K: dim chunk
    const int kp2 = (stid & 15) * 2;     // V f32: key pair
    const int dc  = (stid >> 4) * 8;     // V f32: dim chunk
    const int vd  = stid >> 1;           // V bf16: d row
    const int vko = (stid & 1) * 16;     // V bf16: key half

    float4_t kreg[4], vreg[4];           // f32 path
    short8_t krb[2], vrb[2];             // bf16 path
    if constexpr (CHB) {
        int key = kstart + ki; if (key > T_TOK - 1) key = T_TOK - 1;
        const ushort* kp = Kb + ((long)key * NG + g) * HD + ch;
        krb[0] = *(const short8_t*)kp; krb[1] = *(const short8_t*)(kp + 8);
        int ts = kstart + vko; if (ts > T_TOK - 16) ts = T_TOK - 16;
        const ushort* vp = Vtb + ((long)(g * HD + vd)) * T_TOK + ts;
        vrb[0] = *(const short8_t*)vp; vrb[1] = *(const short8_t*)(vp + 8);
    } else {
        int key = kstart + ki; if (key > T_TOK - 1) key = T_TOK - 1;
        const float* kp = K + ((long)key * NG + g) * HD + ch;
        kreg[0] = *(const float4_t*)kp;       kreg[1] = *(const float4_t*)(kp + 4);
        kreg[2] = *(const float4_t*)(kp + 8); kreg[3] = *(const float4_t*)(kp + 12);
        int key0 = kstart + kp2;     if (key0 > T_TOK - 1) key0 = T_TOK - 1;
        int key1 = kstart + kp2 + 1; if (key1 > T_TOK - 1) key1 = T_TOK - 1;
        const float* v0 = V + ((long)key0 * NG + g) * HD + dc;
        const float* v1 = V + ((long)key1 * NG + g) * HD + dc;
        vreg[0] = *(const float4_t*)v0; vreg[1] = *(const float4_t*)(v0 + 4);
        vreg[2] = *(const float4_t*)v1; vreg[3] = *(const float4_t*)(v1 + 4);
    }

    for (int it = 0; it < nb0; ++it) {
        const int kb = kstart + it * 32;
        __syncthreads();   // previous iter's LDS reads complete

        // ---- write prefetched K/V regs -> LDS (bf16), own split's buffers ----
        if constexpr (CHB) {
            *(short8_t*)&Ks[split][ki][ch]      = krb[0];
            *(short8_t*)&Ks[split][ki][ch + 8]  = krb[1];
            *(short8_t*)&Vt[split][vd][vko]     = vrb[0];
            *(short8_t*)&Vt[split][vd][vko + 8] = vrb[1];
        } else {
            *(short8_t*)&Ks[split][ki][ch]     = cvt8(kreg[0], kreg[1]);
            *(short8_t*)&Ks[split][ki][ch + 8] = cvt8(kreg[2], kreg[3]);
            #pragma unroll
            for (int d = 0; d < 4; ++d) {
                *(unsigned*)&Vt[split][dc + d][kp2]     = pack2(vreg[0][d], vreg[2][d]);
                *(unsigned*)&Vt[split][dc + 4 + d][kp2] = pack2(vreg[1][d], vreg[3][d]);
            }
        }
        __syncthreads();

        // ---- prefetch next 32-key block (in flight during compute) ----
        {
            int nb = kb + 32;
            if constexpr (CHB) {
                int key = nb + ki; if (key > T_TOK - 1) key = T_TOK - 1;
                const ushort* kp = Kb + ((long)key * NG + g) * HD + ch;
                krb[0] = *(const short8_t*)kp; krb[1] = *(const short8_t*)(kp + 8);
                int ts = nb + vko; if (ts > T_TOK - 16) ts = T_TOK - 16;
                const ushort* vp = Vtb + ((long)(g * HD + vd)) * T_TOK + ts;
                vrb[0] = *(const short8_t*)vp; vrb[1] = *(const short8_t*)(vp + 8);
            } else {
                int key = nb + ki; if (key > T_TOK - 1) key = T_TOK - 1;
                const float* kp = K + ((long)key * NG + g) * HD + ch;
                kreg[0] = *(const float4_t*)kp;       kreg[1] = *(const float4_t*)(kp + 4);
                kreg[2] = *(const float4_t*)(kp + 8); kreg[3] = *(const float4_t*)(kp + 12);
                int key0 = nb + kp2;     if (key0 > T_TOK - 1) key0 = T_TOK - 1;
                int key1 = nb + kp2 + 1; if (key1 > T_TOK - 1) key1 = T_TOK - 1;
                const float* v0 = V + ((long)key0 * NG + g) * HD + dc;
                const float* v1 = V + ((long)key1 * NG + g) * HD + dc;
                vreg[0] = *(const float4_t*)v0; vreg[1] = *(const float4_t*)(v0 + 4);
                vreg[2] = *(const float4_t*)v1; vreg[3] = *(const float4_t*)(v1 + 4);
            }
        }

        // ---- S^T tiles: 8 K-frag reads feed 16 MFMAs (2 q-tiles) ----
        float4_t st[2][2];
        #pragma unroll
        for (int tt = 0; tt < 2; ++tt)
            #pragma unroll
            for (int t = 0; t < 2; ++t) st[tt][t] = (float4_t){0.f, 0.f, 0.f, 0.f};
        #pragma unroll
        for (int c = 0; c < 4; ++c) {
            short8_t kf0 = *(const short8_t*)&Ks[split][col][c * 32 + quad * 8];
            short8_t kf1 = *(const short8_t*)&Ks[split][16 + col][c * 32 + quad * 8];
            st[0][0] = __builtin_amdgcn_mfma_f32_16x16x32_bf16(kf0, qf[0][c], st[0][0], 0, 0, 0);
            st[0][1] = __builtin_amdgcn_mfma_f32_16x16x32_bf16(kf1, qf[0][c], st[0][1], 0, 0, 0);
            st[1][0] = __builtin_amdgcn_mfma_f32_16x16x32_bf16(kf0, qf[1][c], st[1][0], 0, 0, 0);
            st[1][1] = __builtin_amdgcn_mfma_f32_16x16x32_bf16(kf1, qf[1][c], st[1][1], 0, 0, 0);
        }

        // ---- mask + online softmax per q-tile (log2 domain) ----
        #pragma unroll
        for (int tt = 0; tt < 2; ++tt) {
            float tv[8];
            // interior fast-path: all 32 keys valid for all 16 q rows
            if (kb + 31 <= qbase + 16 * tt && kb >= smax[tt]) {
                #pragma unroll
                for (int i = 0; i < 8; ++i)
                    tv[i] = st[tt][i >> 2][i & 3] * c_scale;
            } else {
                #pragma unroll
                for (int t = 0; t < 2; ++t)
                    #pragma unroll
                    for (int r = 0; r < 4; ++r) {
                        int key = kb + 16 * t + quad * 4 + r;
                        bool valid = (key <= qq[tt]) && (key >= seg_start[tt]);
                        tv[t * 4 + r] = valid ? st[tt][t][r] * c_scale : -30000.0f;
                    }
            }
            float tmax = tv[0];
            #pragma unroll
            for (int i = 1; i < 8; ++i) tmax = fmaxf(tmax, tv[i]);
            tmax = fmaxf(tmax, __shfl_xor(tmax, 16));
            tmax = fmaxf(tmax, __shfl_xor(tmax, 32));
            const float m_new = fmaxf(m_run[tt], tmax);
            float p[8], ps = 0.f;
            #pragma unroll
            for (int i = 0; i < 8; ++i) { p[i] = __builtin_exp2f(tv[i] - m_new); ps += p[i]; }
            ps += __shfl_xor(ps, 16);
            ps += __shfl_xor(ps, 32);
            // defer-rescale: alpha==1 exactly when no lane's max grew
            if (__any(tmax > m_run[tt])) {
                const float alpha = __builtin_exp2f(m_run[tt] - m_new);
                l_run[tt] = l_run[tt] * alpha + ps;
                m_run[tt] = m_new;
                #pragma unroll
                for (int dt = 0; dt < 8; ++dt) oacc[tt][dt] *= alpha;
            } else {
                l_run[tt] += ps;
            }

            uint2_t w0; w0.x = pack2(p[0], p[1]); w0.y = pack2(p[2], p[3]);
            uint2_t w1; w1.x = pack2(p[4], p[5]); w1.y = pack2(p[6], p[7]);
            *(uint2_t*)&pb[wave][tt][col][quad * 4]      = w0;
            *(uint2_t*)&pb[wave][tt][col][16 + quad * 4] = w1;
        }
        short8_t pf0 = *(const short8_t*)&pb[wave][0][col][quad * 8];
        short8_t pf1 = *(const short8_t*)&pb[wave][1][col][quad * 8];

        // ---- O^T += V^T * P^T : 8 V-frag reads feed 16 MFMAs ----
        #pragma unroll
        for (int dt = 0; dt < 8; ++dt) {
            short8_t vf = *(const short8_t*)&Vt[split][dt * 16 + col][quad * 8];
            oacc[0][dt] = __builtin_amdgcn_mfma_f32_16x16x32_bf16(vf, pf0, oacc[0][dt], 0, 0, 0);
            oacc[1][dt] = __builtin_amdgcn_mfma_f32_16x16x32_bf16(vf, pf1, oacc[1][dt], 0, 0, 0);
        }
    }

    // ---- merge split1's (m,l,O) into split0 via LDS (region reuse) ----
    float* Ob = (float*)smem;                  // [4 heads][16 q][132] floats
    float* cm = (float*)(smem + 34816);        // 64 floats per pass
    float* cl = (float*)(smem + 35840);
    #pragma unroll
    for (int tt = 0; tt < 2; ++tt) {
        __syncthreads();
        if (split == 1) {
            if (quad == 0) { cm[hw * 16 + col] = m_run[tt]; cl[hw * 16 + col] = l_run[tt]; }
            float* ob = Ob + (hw * 16 + col) * 132;
            #pragma unroll
            for (int dt = 0; dt < 8; ++dt)
                *(float4_t*)(ob + dt * 16 + quad * 4) = oacc[tt][dt];
        }
        __syncthreads();
        if (split == 0) {
            const float m1 = cm[hw * 16 + col], l1 = cl[hw * 16 + col];
            const float m  = fmaxf(m_run[tt], m1);
            const float a0 = __builtin_exp2f(m_run[tt] - m);
            const float a1 = __builtin_exp2f(m1 - m);
            const float* ob = Ob + (hw * 16 + col) * 132;
            #pragma unroll
            for (int dt = 0; dt < 8; ++dt) {
                float4_t o1 = *(const float4_t*)(ob + dt * 16 + quad * 4);
                oacc[tt][dt] = oacc[tt][dt] * a0 + o1 * a1;
            }
            l_run[tt] = l_run[tt] * a0 + l1 * a1;
            m_run[tt] = m;   // commit merged max: partial path stores (m,l,O)
                             // and all three must share one reference max
        }
    }

    // ---- epilogue ----
    if (!CHB || nc == 1) {
        if (split == 0) {
            // whole span in this item: normalized direct store
            #pragma unroll
            for (int tt = 0; tt < 2; ++tt) {
                const float inv_l = 1.0f / l_run[tt];
                float* op = O + ((long)qq[tt] * NH + h) * HD + quad * 4;
                #pragma unroll
                for (int dt = 0; dt < 8; ++dt) {
                    float4_t ov;
                    #pragma unroll
                    for (int r = 0; r < 4; ++r) ov[r] = oacc[tt][dt][r] * inv_l;
                    *(float4_t*)(op + dt * 16) = ov;
                }
            }
        }
        return;
    }

    // ---- multi-chunk: write bf16 partial (m,l f32; O bf16) ----
    const long slot = ((long)(qtile * 4 + g)) * 8 + cz;
    if (split == 0) {
        ushort* ob = (ushort*)WS + slot * 16384;
        #pragma unroll
        for (int tt = 0; tt < 2; ++tt) {
            const int row = hw * 32 + tt * 16 + col;
            if (quad == 0) {
                float* mlp = WS + ML_OFF + slot * 256 + row * 2;
                mlp[0] = m_run[tt];
                mlp[1] = l_run[tt];
            }
            ushort* op = ob + row * 128 + quad * 4;
            #pragma unroll
            for (int dt = 0; dt < 8; ++dt) {
                uint2_t w;
                w.x = pack2(oacc[tt][dt][0], oacc[tt][dt][1]);
                w.y = pack2(oacc[tt][dt][2], oacc[tt][dt][3]);
                *(uint2_t*)(op + dt * 16) = w;
            }
        }
    }

    // ---- semaphore: last-finishing chunk merges (device-scope, G16) ----
    __threadfence();                       // release this block's stores
    __syncthreads();
    int* flag = (int*)(smem + 37888);      // pb region free post-loop
    if (tid == 0) {
        int* cnt = (int*)(WS + CNT_OFF);
        *flag = atomicAdd(&cnt[qtile * 4 + g], 1);
    }
    __syncthreads();
    const bool last = (*flag == nc - 1);
    if (!last) return;
    __threadfence();                       // acquire before reading partials

    // inline merge: 512 threads; thread -> (row = hw*32+q, 32-d segment)
    {
        const int row  = tid >> 2;         // 0..127
        const int dseg = (tid & 3) * 32;
        float m = -30000.0f, l = 0.0f;
        float4_t acc[8];
        #pragma unroll
        for (int i = 0; i < 8; ++i) acc[i] = (float4_t){0.f, 0.f, 0.f, 0.f};
        const long sbase = ((long)(qtile * 4 + g)) * 8;
        for (int c = 0; c < nc; ++c) {
            const float* mlp = WS + ML_OFF + (sbase + c) * 256 + row * 2;
            const float mc = mlp[0], lc = mlp[1];
            const float mn = fmaxf(m, mc);
            const float a0 = __builtin_exp2f(m - mn);
            const float a1 = __builtin_exp2f(mc - mn);
            l = l * a0 + lc * a1;
            const ushort* op = (const ushort*)WS + (sbase + c) * 16384 + row * 128 + dseg;
            #pragma unroll
            for (int i = 0; i < 8; ++i) {
                float4_t v;
                v[0] = bf2f(op[i * 4 + 0]); v[1] = bf2f(op[i * 4 + 1]);
                v[2] = bf2f(op[i * 4 + 2]); v[3] = bf2f(op[i * 4 + 3]);
                acc[i] = acc[i] * a0 + v * a1;
            }
            m = mn;
        }
        const float inv = 1.0f / l;
        const int q = row & 31, hwm = row >> 5;
        float* o = O + ((long)(qbase + q) * NH + g * 4 + hwm) * HD + dseg;
        #pragma unroll
        for (int i = 0; i < 8; ++i)
            *(float4_t*)(o + i * 4) = acc[i] * inv;
    }
}

// ---- persistent kernel: 512 resident blocks pop live items ----
__global__ __launch_bounds__(512) void attn_fwd_persist(
    const float* __restrict__ Q,
    const float* __restrict__ K,
    const float* __restrict__ V,
    const int*   __restrict__ cu,
    float*       __restrict__ O,
    float*       __restrict__ WS)
{
    __shared__ __align__(16) unsigned char smem[58368];
    __shared__ int pop_s;
    int* qwork = (int*)(WS + Q_OFF);
    const ushort* Kb  = (const ushort*)(WS + KBF_OFF);
    const ushort* Vtb = (const ushort*)(WS + VTB_OFF);
    const int qtotal = qwork[0];

    for (;;) {
        __syncthreads();                       // prior item's smem use done
        if (threadIdx.x == 0) pop_s = atomicAdd(&qwork[1], 1);
        __syncthreads();
        const int idx = pop_s;                 // block-uniform
        if (idx >= qtotal) return;
        const int ent = qwork[2 + idx];
        attn_tile_body<true>(Q, K, V, Kb, Vtb, cu, O, WS, smem,
                             ent >> 5, (ent >> 3) & 3, ent & 7);
    }
}

// ---- monolithic fallback (no workspace dependence) ----
__global__ __launch_bounds__(512) void attn_fwd_mono(
    const float* __restrict__ Q,
    const float* __restrict__ K,
    const float* __restrict__ V,
    const int*   __restrict__ cu,
    float*       __restrict__ O)
{
    __shared__ __align__(16) unsigned char smem[58368];
    attn_tile_body<false>(Q, K, V, nullptr, nullptr, cu, O, nullptr, smem,
                          (int)gridDim.x - 1 - (int)blockIdx.x,
                          (int)blockIdx.y, 0);
}

extern "C" void kernel_launch(void* const* d_in, const int* in_sizes, int n_in,
                              void* d_out, int out_size, void* d_ws, size_t ws_size,
                              hipStream_t stream) {
    const float* Q  = (const float*)d_in[0];
    const float* K  = (const float*)d_in[1];
    const float* V  = (const float*)d_in[2];
    const int*   cu = (const int*)d_in[3];
    float*       O  = (float*)d_out;
    const size_t need = (size_t)WS_END * sizeof(float);   // 146.8 MB
    if (d_ws != nullptr && ws_size >= need) {
        float* WS = (float*)d_ws;
        prep_all<<<1537, 256, 0, stream>>>(K, V, cu, WS);
        attn_fwd_persist<<<512, 512, 0, stream>>>(Q, K, V, cu, O, WS);
    } else {
        attn_fwd_mono<<<dim3(T_TOK / 32, NG), 512, 0, stream>>>(Q, K, V, cu, O);
    }
}

// Round 9
// 200.433 us; speedup vs baseline: 2.4668x; 2.4668x over previous
//
#include <hip/hip_runtime.h>
#include <hip/hip_bf16.h>

// Packed varlen causal GQA attention (flash-style), MI355X gfx950.
// Q [T,H,D] f32, K/V [T,G,D] f32, cu_seqlens [9] int32 -> O [T,H,D] f32.
// T=4096, H=16, G=4, D=128, SCALE=1/sqrt(128).
//
// R17 = R15's fence-free structure (persistent queue + bf16 K/V staging,
// fwd 72us verified) + finer uniform chunks + bf16 partials + fused prep.
// R16 POST-MORTEM: inline cross-block merge needed __threadfence
// (device scope) -> L2 writeback/invalidate per item -> destroyed the
// Kbf/Vtb L2 reuse machine-wide (MfmaUtil 1.9%, fwd 448us). Kernel-
// boundary visibility (separate merge dispatch) is the correct and free
// coherence mechanism on CDNA4 -- fences stay OUT of the hot kernel.
//  1. chunk geometry: nc0=min(8,ceil(nblk/12)), chunk=even_ceil(nblk/nc0),
//     nc_eff=ceil(nblk/chunk) -- ONE helper used by build/body/merge
//     (fixes R16 edge: cz*chunk could pass span end leaving a phantom
//     chunk). Longest item 16->8 iters; ~860 items for 512 workers;
//     R15's makespan was the single longest item (16 iters ~ 72us).
//  2. partials stored bf16 (O) + f32 (m,l): half the partial traffic;
//     merge accumulates f32. absmax budget +~0.004 (threshold 0.071).
//  3. prep fused: K cvt + V transpose + queue build, one dispatch, no
//     Qbf (Q converted in-body once per item, ~2x reuse only).
// R14 lessons kept: no shfl P-reshuffle, pb LDS round-trip stays, 2
// barriers/iter, staging writes after barrier.
//
// Per item: 512 threads = 8 waves; waves 0-3 (split 0) handle heads
// g*4+0..3 over the first half of the chunk's key range; waves 4-7
// (split 1) the second half. Independent (m,l,O) per split, merged via
// LDS; merged max committed back into m_run (R10 fix) so stored partials
// (m,l,O) share one reference max. Defer-rescale: skip oacc*=alpha when
// no lane's max grew (exact). Mask fast-path on interior iterations.
// MFMA layouts (HW-verified m89/m91/m118-m122), 16x16x32_bf16:
//   A[m=lane&15][k=quad*8+j], B[k=quad*8+j][n=lane&15],
//   C/D: row m = quad*4+reg, col n = lane&15.

#define T_TOK 4096
#define NH    16
#define NG    4
#define HD    128
#define NCU   9
#define NTILE 128

// Workspace layout (float-element offsets):
//   O_part bf16 [tile128][g4][chunk8][row128][d128]    = 33,554,432 f-slots
//   ml  f32   [tile][g][chunk8][row128][{m,l}]         =  1,048,576 f
//   queue (ints): [0]=total,[1]=pop,[2..4097]=entries  =      4,100 f
//   (pad)                                              =        512 f
//   Kbf [t][g][d] bf16                                 =  1,048,576 f
//   Vtb [g][d][t] bf16 (pre-transposed)                =  1,048,576 f
#define ML_OFF  33554432l
#define Q_OFF   34603008l
#define KBF_OFF 34607620l
#define VTB_OFF 35656196l
#define WS_END  36704772l

typedef short          short8_t __attribute__((ext_vector_type(8)));
typedef float          float4_t __attribute__((ext_vector_type(4)));
typedef unsigned int   uint2_t  __attribute__((ext_vector_type(2)));
typedef unsigned short ushort;

static __device__ inline unsigned pack2(float a, float b) {
    __hip_bfloat162 h = __float22bfloat162_rn(make_float2(a, b));
    union { __hip_bfloat162 h; unsigned u; } c; c.h = h;
    return c.u;
}
static __device__ inline short8_t cvt8(float4_t lo, float4_t hi) {
    union { unsigned u[4]; short8_t s; } r;
    r.u[0] = pack2(lo[0], lo[1]); r.u[1] = pack2(lo[2], lo[3]);
    r.u[2] = pack2(hi[0], hi[1]); r.u[3] = pack2(hi[2], hi[3]);
    return r.s;
}
static __device__ inline float bf2f(ushort u) {
    union { unsigned i; float f; } c; c.i = ((unsigned)u) << 16; return c.f;
}
// chunk geometry -- MUST be identical in build/body/merge.
// nc0 = min(8, ceil(nblk/12)); chunk = even_ceil(nblk/nc0);
// nc_eff = ceil(nblk/chunk)  (no phantom chunks past span end)
static __device__ __forceinline__ void chunk_geom(int nblk, int& chunk, int& nce) {
    int nc0 = (nblk + 11) / 12;
    if (nc0 > 8) nc0 = 8;
    chunk = (((nblk + nc0 - 1) / nc0) + 1) & ~1;
    nce   = (nblk + chunk - 1) / chunk;
}

// ---- prep: K f32->bf16, V f32->bf16 transposed [g][d][t], build queue ----
#define NPK 1048576l   // K bf16 pairs
__global__ __launch_bounds__(256) void prep_all(
    const float* __restrict__ K, const float* __restrict__ V,
    const int* __restrict__ cu, float* __restrict__ WS)
{
    const int b = (int)blockIdx.x, tid = (int)threadIdx.x;
    if (b < 512) {
        // K convert (flat pairs)
        unsigned* Kb = (unsigned*)(WS + KBF_OFF);
        for (long p = (long)b * 256 + tid; p < NPK; p += 512l * 256) {
            const float2 v = *(const float2*)&K[2 * p];
            Kb[p] = pack2(v.x, v.y);
        }
    } else if (b < 1536) {
        // V transpose: tile 64 t x 32 d per block, via LDS (R15-verified)
        ushort* Vtb = (ushort*)(WS + VTB_OFF);
        const int bt  = b - 512;             // 0..1023
        const int g   = bt >> 8;             // 4
        const int rem = bt & 255;            // 4 d-tiles x 64 t-tiles
        const int d0  = (rem >> 6) * 32;
        const int t0  = (rem & 63) * 64;
        __shared__ ushort tile[64][36];
        const int i2 = tid >> 3, jl = (tid & 7) * 4;
        #pragma unroll
        for (int ii = 0; ii < 2; ++ii) {
            const int t = t0 + i2 + ii * 32;
            const float4_t v = *(const float4_t*)&V[((long)t * NG + g) * HD + d0 + jl];
            *(unsigned*)&tile[i2 + ii * 32][jl]     = pack2(v[0], v[1]);
            *(unsigned*)&tile[i2 + ii * 32][jl + 2] = pack2(v[2], v[3]);
        }
        __syncthreads();
        const int jj = tid >> 3, tl = (tid & 7) * 8;
        union { ushort s[8]; short8_t v; } o;
        #pragma unroll
        for (int r = 0; r < 8; ++r) o.s[r] = tile[tl + r][jj];
        *(short8_t*)&Vtb[((long)(g * HD + d0 + jj)) * T_TOK + t0 + tl] = o.v;
    } else {
        // build queue (heaviest tiles first)
        int* qwork = (int*)(WS + Q_OFF);
        __shared__ int nblk_s[NTILE];
        __shared__ int sortedE[NTILE + 1];
        if (tid >= 128) return;
        const int t = tid;                   // tile id 0..127
        const int qbase = t * 32;
        int seg0 = 0;
        #pragma unroll
        for (int j = 1; j < NCU; ++j) { int cj = cu[j]; if (cj <= qbase) seg0 = cj; }
        const int k0   = seg0 & ~31;
        const int nblk = (qbase + 32 - k0) >> 5;   // 1..128
        nblk_s[t] = nblk;
        __syncthreads();
        // rank by (nblk desc, tile asc) -- strict total order
        int r = 0;
        for (int j = 0; j < NTILE; ++j) {
            int nj = nblk_s[j];
            if (nj > nblk || (nj == nblk && j < t)) ++r;
        }
        int chunk, nce; chunk_geom(nblk, chunk, nce);
        sortedE[r] = 4 * nce;
        __syncthreads();
        if (t == 0) {
            int s = 0;
            for (int j = 0; j < NTILE; ++j) { int v = sortedE[j]; sortedE[j] = s; s += v; }
            sortedE[NTILE] = s;
            qwork[0] = s;
            qwork[1] = 0;
        }
        __syncthreads();
        int off = 2 + sortedE[r];
        for (int g = 0; g < NG; ++g)
            for (int cz = 0; cz < nce; ++cz)
                qwork[off++] = (t << 5) | (g << 3) | cz;   // tile:7|g:2|cz:3
    }
}

// ---- tile body. CHB: false = mono f32 direct, true = chunked bf16 ----
template <bool CHB>
static __device__ __forceinline__ void attn_tile_body(
    const float* __restrict__ Q, const float* __restrict__ K,
    const float* __restrict__ V,
    const ushort* __restrict__ Kb, const ushort* __restrict__ Vtb,
    const int* __restrict__ cu,
    float* __restrict__ O, float* __restrict__ WS,
    unsigned char* smem, int qtile, int g, int cz)
{
    ushort (*Ks)[32][136]   = (ushort (*)[32][136])smem;
    ushort (*Vt)[128][40]   = (ushort (*)[128][40])(smem + 17408);
    ushort (*pb)[2][16][40] = (ushort (*)[2][16][40])(smem + 37888);

    const int tid   = threadIdx.x;
    const int wave  = tid >> 6;          // 0..7
    const int split = wave >> 2;         // 0..1 (key-range half)
    const int hw    = wave & 3;
    const int lane  = tid & 63;
    const int h     = g * 4 + hw;        // query head; h//4 == g (jnp.repeat)
    const int col   = lane & 15;
    const int quad  = lane >> 4;

    const int qbase = qtile * 32;        // 32 q rows per block
    const int qq[2] = { qbase + col, qbase + 16 + col };

    // segment starts: per-lane per-tile, and block-uniform for k0
    int seg_start[2] = {0, 0}, seg0 = 0;
    #pragma unroll
    for (int j = 1; j < NCU; ++j) {
        int cj = cu[j];
        if (cj <= qq[0])  seg_start[0] = cj;
        if (cj <= qq[1])  seg_start[1] = cj;
        if (cj <= qbase)  seg0         = cj;
    }
    const int k0       = seg0 & ~31;
    const int nblk_tot = (qbase + 32 - k0) >> 5;      // 32-key blocks in span

    int nc = 1, kb_lo = 0, nblk = nblk_tot;
    if (CHB) {
        int chunk; chunk_geom(nblk_tot, chunk, nc);
        if (cz >= nc) return;                         // defensive (unreached)
        kb_lo = cz * chunk;
        nblk  = nblk_tot - kb_lo;
        if (nblk > chunk) nblk = chunk;
    }
    const int nb0    = (nblk + 1) >> 1;               // iterations per split
    const int kstart = k0 + (kb_lo + split * nb0) * 32;

    // wave-uniform max seg_start per q-tile (seg_start monotone in col)
    const int smax[2] = { __shfl(seg_start[0], 15), __shfl(seg_start[1], 15) };

    // Q fragments (B-operand of S^T = K*Q^T), 2 tiles. dim = c*32+quad*8+j.
    short8_t qf[2][4];
    #pragma unroll
    for (int tt = 0; tt < 2; ++tt) {
        const float* qp = Q + ((long)qq[tt] * NH + h) * HD + quad * 8;
        #pragma unroll
        for (int c = 0; c < 4; ++c)
            qf[tt][c] = cvt8(*(const float4_t*)(qp + c * 32),
                             *(const float4_t*)(qp + c * 32 + 4));
    }

    float4_t oacc[2][8];
    #pragma unroll
    for (int tt = 0; tt < 2; ++tt)
        #pragma unroll
        for (int dt = 0; dt < 8; ++dt) oacc[tt][dt] = (float4_t){0.f, 0.f, 0.f, 0.f};

    float m_run[2] = {-10000.0f, -10000.0f};
    float l_run[2] = {0.0f, 0.0f};
    const float c_scale = 0.08838834764831845f * 1.4426950408889634f; // SCALE*log2e

    // staging thread mapping (256 threads per split, 32 keys x 128 dims)
    const int stid = tid & 255;
    const int ki  = stid >> 3;           // K: key-in-tile
    const int ch  = (stid & 7) * 16;     // K: dim chunk
    const int kp2 = (stid & 15) * 2;     // V f32: key pair
    const int dc  = (stid >> 4) * 8;     // V f32: dim chunk
    const int vd  = stid >> 1;           // V bf16: d row
    const int vko = (stid & 1) * 16;     // V bf16: key half

    float4_t kreg[4], vreg[4];           // f32 path
    short8_t krb[2], vrb[2];             // bf16 path
    if constexpr (CHB) {
        int key = kstart + ki; if (key > T_TOK - 1) key = T_TOK - 1;
        const ushort* kp = Kb + ((long)key * NG + g) * HD + ch;
        krb[0] = *(const short8_t*)kp; krb[1] = *(const short8_t*)(kp + 8);
        int ts = kstart + vko; if (ts > T_TOK - 16) ts = T_TOK - 16;
        const ushort* vp = Vtb + ((long)(g * HD + vd)) * T_TOK + ts;
        vrb[0] = *(const short8_t*)vp; vrb[1] = *(const short8_t*)(vp + 8);
    } else {
        int key = kstart + ki; if (key > T_TOK - 1) key = T_TOK - 1;
        const float* kp = K + ((long)key * NG + g) * HD + ch;
        kreg[0] = *(const float4_t*)kp;       kreg[1] = *(const float4_t*)(kp + 4);
        kreg[2] = *(const float4_t*)(kp + 8); kreg[3] = *(const float4_t*)(kp + 12);
        int key0 = kstart + kp2;     if (key0 > T_TOK - 1) key0 = T_TOK - 1;
        int key1 = kstart + kp2 + 1; if (key1 > T_TOK - 1) key1 = T_TOK - 1;
        const float* v0 = V + ((long)key0 * NG + g) * HD + dc;
        const float* v1 = V + ((long)key1 * NG + g) * HD + dc;
        vreg[0] = *(const float4_t*)v0; vreg[1] = *(const float4_t*)(v0 + 4);
        vreg[2] = *(const float4_t*)v1; vreg[3] = *(const float4_t*)(v1 + 4);
    }

    for (int it = 0; it < nb0; ++it) {
        const int kb = kstart + it * 32;
        __syncthreads();   // previous iter's LDS reads complete

        // ---- write prefetched K/V regs -> LDS (bf16), own split's buffers ----
        if constexpr (CHB) {
            *(short8_t*)&Ks[split][ki][ch]      = krb[0];
            *(short8_t*)&Ks[split][ki][ch + 8]  = krb[1];
            *(short8_t*)&Vt[split][vd][vko]     = vrb[0];
            *(short8_t*)&Vt[split][vd][vko + 8] = vrb[1];
        } else {
            *(short8_t*)&Ks[split][ki][ch]     = cvt8(kreg[0], kreg[1]);
            *(short8_t*)&Ks[split][ki][ch + 8] = cvt8(kreg[2], kreg[3]);
            #pragma unroll
            for (int d = 0; d < 4; ++d) {
                *(unsigned*)&Vt[split][dc + d][kp2]     = pack2(vreg[0][d], vreg[2][d]);
                *(unsigned*)&Vt[split][dc + 4 + d][kp2] = pack2(vreg[1][d], vreg[3][d]);
            }
        }
        __syncthreads();

        // ---- prefetch next 32-key block (in flight during compute) ----
        {
            int nb = kb + 32;
            if constexpr (CHB) {
                int key = nb + ki; if (key > T_TOK - 1) key = T_TOK - 1;
                const ushort* kp = Kb + ((long)key * NG + g) * HD + ch;
                krb[0] = *(const short8_t*)kp; krb[1] = *(const short8_t*)(kp + 8);
                int ts = nb + vko; if (ts > T_TOK - 16) ts = T_TOK - 16;
                const ushort* vp = Vtb + ((long)(g * HD + vd)) * T_TOK + ts;
                vrb[0] = *(const short8_t*)vp; vrb[1] = *(const short8_t*)(vp + 8);
            } else {
                int key = nb + ki; if (key > T_TOK - 1) key = T_TOK - 1;
                const float* kp = K + ((long)key * NG + g) * HD + ch;
                kreg[0] = *(const float4_t*)kp;       kreg[1] = *(const float4_t*)(kp + 4);
                kreg[2] = *(const float4_t*)(kp + 8); kreg[3] = *(const float4_t*)(kp + 12);
                int key0 = nb + kp2;     if (key0 > T_TOK - 1) key0 = T_TOK - 1;
                int key1 = nb + kp2 + 1; if (key1 > T_TOK - 1) key1 = T_TOK - 1;
                const float* v0 = V + ((long)key0 * NG + g) * HD + dc;
                const float* v1 = V + ((long)key1 * NG + g) * HD + dc;
                vreg[0] = *(const float4_t*)v0; vreg[1] = *(const float4_t*)(v0 + 4);
                vreg[2] = *(const float4_t*)v1; vreg[3] = *(const float4_t*)(v1 + 4);
            }
        }

        // ---- S^T tiles: 8 K-frag reads feed 16 MFMAs (2 q-tiles) ----
        float4_t st[2][2];
        #pragma unroll
        for (int tt = 0; tt < 2; ++tt)
            #pragma unroll
            for (int t = 0; t < 2; ++t) st[tt][t] = (float4_t){0.f, 0.f, 0.f, 0.f};
        #pragma unroll
        for (int c = 0; c < 4; ++c) {
            short8_t kf0 = *(const short8_t*)&Ks[split][col][c * 32 + quad * 8];
            short8_t kf1 = *(const short8_t*)&Ks[split][16 + col][c * 32 + quad * 8];
            st[0][0] = __builtin_amdgcn_mfma_f32_16x16x32_bf16(kf0, qf[0][c], st[0][0], 0, 0, 0);
            st[0][1] = __builtin_amdgcn_mfma_f32_16x16x32_bf16(kf1, qf[0][c], st[0][1], 0, 0, 0);
            st[1][0] = __builtin_amdgcn_mfma_f32_16x16x32_bf16(kf0, qf[1][c], st[1][0], 0, 0, 0);
            st[1][1] = __builtin_amdgcn_mfma_f32_16x16x32_bf16(kf1, qf[1][c], st[1][1], 0, 0, 0);
        }

        // ---- mask + online softmax per q-tile (log2 domain) ----
        #pragma unroll
        for (int tt = 0; tt < 2; ++tt) {
            float tv[8];
            // interior fast-path: all 32 keys valid for all 16 q rows
            if (kb + 31 <= qbase + 16 * tt && kb >= smax[tt]) {
                #pragma unroll
                for (int i = 0; i < 8; ++i)
                    tv[i] = st[tt][i >> 2][i & 3] * c_scale;
            } else {
                #pragma unroll
                for (int t = 0; t < 2; ++t)
                    #pragma unroll
                    for (int r = 0; r < 4; ++r) {
                        int key = kb + 16 * t + quad * 4 + r;
                        bool valid = (key <= qq[tt]) && (key >= seg_start[tt]);
                        tv[t * 4 + r] = valid ? st[tt][t][r] * c_scale : -30000.0f;
                    }
            }
            float tmax = tv[0];
            #pragma unroll
            for (int i = 1; i < 8; ++i) tmax = fmaxf(tmax, tv[i]);
            tmax = fmaxf(tmax, __shfl_xor(tmax, 16));
            tmax = fmaxf(tmax, __shfl_xor(tmax, 32));
            const float m_new = fmaxf(m_run[tt], tmax);
            float p[8], ps = 0.f;
            #pragma unroll
            for (int i = 0; i < 8; ++i) { p[i] = __builtin_exp2f(tv[i] - m_new); ps += p[i]; }
            ps += __shfl_xor(ps, 16);
            ps += __shfl_xor(ps, 32);
            // defer-rescale: alpha==1 exactly when no lane's max grew
            if (__any(tmax > m_run[tt])) {
                const float alpha = __builtin_exp2f(m_run[tt] - m_new);
                l_run[tt] = l_run[tt] * alpha + ps;
                m_run[tt] = m_new;
                #pragma unroll
                for (int dt = 0; dt < 8; ++dt) oacc[tt][dt] *= alpha;
            } else {
                l_run[tt] += ps;
            }

            uint2_t w0; w0.x = pack2(p[0], p[1]); w0.y = pack2(p[2], p[3]);
            uint2_t w1; w1.x = pack2(p[4], p[5]); w1.y = pack2(p[6], p[7]);
            *(uint2_t*)&pb[wave][tt][col][quad * 4]      = w0;
            *(uint2_t*)&pb[wave][tt][col][16 + quad * 4] = w1;
        }
        short8_t pf0 = *(const short8_t*)&pb[wave][0][col][quad * 8];
        short8_t pf1 = *(const short8_t*)&pb[wave][1][col][quad * 8];

        // ---- O^T += V^T * P^T : 8 V-frag reads feed 16 MFMAs ----
        #pragma unroll
        for (int dt = 0; dt < 8; ++dt) {
            short8_t vf = *(const short8_t*)&Vt[split][dt * 16 + col][quad * 8];
            oacc[0][dt] = __builtin_amdgcn_mfma_f32_16x16x32_bf16(vf, pf0, oacc[0][dt], 0, 0, 0);
            oacc[1][dt] = __builtin_amdgcn_mfma_f32_16x16x32_bf16(vf, pf1, oacc[1][dt], 0, 0, 0);
        }
    }

    // ---- merge split1's (m,l,O) into split0 via LDS (region reuse) ----
    float* Ob = (float*)smem;                  // [4 heads][16 q][132] floats
    float* cm = (float*)(smem + 34816);        // 64 floats per pass
    float* cl = (float*)(smem + 35840);
    #pragma unroll
    for (int tt = 0; tt < 2; ++tt) {
        __syncthreads();
        if (split == 1) {
            if (quad == 0) { cm[hw * 16 + col] = m_run[tt]; cl[hw * 16 + col] = l_run[tt]; }
            float* ob = Ob + (hw * 16 + col) * 132;
            #pragma unroll
            for (int dt = 0; dt < 8; ++dt)
                *(float4_t*)(ob + dt * 16 + quad * 4) = oacc[tt][dt];
        }
        __syncthreads();
        if (split == 0) {
            const float m1 = cm[hw * 16 + col], l1 = cl[hw * 16 + col];
            const float m  = fmaxf(m_run[tt], m1);
            const float a0 = __builtin_exp2f(m_run[tt] - m);
            const float a1 = __builtin_exp2f(m1 - m);
            const float* ob = Ob + (hw * 16 + col) * 132;
            #pragma unroll
            for (int dt = 0; dt < 8; ++dt) {
                float4_t o1 = *(const float4_t*)(ob + dt * 16 + quad * 4);
                oacc[tt][dt] = oacc[tt][dt] * a0 + o1 * a1;
            }
            l_run[tt] = l_run[tt] * a0 + l1 * a1;
            m_run[tt] = m;   // commit merged max: partial path stores (m,l,O)
                             // and all three must share one reference max
        }
    }

    // ---- epilogue (split 0 only) ----
    if (split == 0) {
        if (!CHB || nc == 1) {
            // whole span in this item: normalized direct store
            #pragma unroll
            for (int tt = 0; tt < 2; ++tt) {
                const float inv_l = 1.0f / l_run[tt];
                float* op = O + ((long)qq[tt] * NH + h) * HD + quad * 4;
                #pragma unroll
                for (int dt = 0; dt < 8; ++dt) {
                    float4_t ov;
                    #pragma unroll
                    for (int r = 0; r < 4; ++r) ov[r] = oacc[tt][dt][r] * inv_l;
                    *(float4_t*)(op + dt * 16) = ov;
                }
            }
        } else {
            // multi-chunk: bf16 O partial + f32 (m,l) to workspace
            const long slot = ((long)(qtile * 4 + g)) * 8 + cz;
            ushort* ob = (ushort*)WS + slot * 16384;
            #pragma unroll
            for (int tt = 0; tt < 2; ++tt) {
                const int row = hw * 32 + tt * 16 + col;
                if (quad == 0) {
                    float* mlp = WS + ML_OFF + slot * 256 + row * 2;
                    mlp[0] = m_run[tt];
                    mlp[1] = l_run[tt];
                }
                ushort* op = ob + row * 128 + quad * 4;
                #pragma unroll
                for (int dt = 0; dt < 8; ++dt) {
                    uint2_t w;
                    w.x = pack2(oacc[tt][dt][0], oacc[tt][dt][1]);
                    w.y = pack2(oacc[tt][dt][2], oacc[tt][dt][3]);
                    *(uint2_t*)(op + dt * 16) = w;
                }
            }
        }
    }
}

// ---- persistent kernel: 512 resident blocks pop live items ----
__global__ __launch_bounds__(512) void attn_fwd_persist(
    const float* __restrict__ Q,
    const float* __restrict__ K,
    const float* __restrict__ V,
    const int*   __restrict__ cu,
    float*       __restrict__ O,
    float*       __restrict__ WS)
{
    __shared__ __align__(16) unsigned char smem[58368];
    __shared__ int pop_s;
    int* qwork = (int*)(WS + Q_OFF);
    const ushort* Kb  = (const ushort*)(WS + KBF_OFF);
    const ushort* Vtb = (const ushort*)(WS + VTB_OFF);
    const int qtotal = qwork[0];

    for (;;) {
        __syncthreads();                       // prior item's smem use done
        if (threadIdx.x == 0) pop_s = atomicAdd(&qwork[1], 1);
        __syncthreads();
        const int idx = pop_s;                 // block-uniform
        if (idx >= qtotal) return;
        const int ent = qwork[2 + idx];
        attn_tile_body<true>(Q, K, V, Kb, Vtb, cu, O, WS, smem,
                             ent >> 5, (ent >> 3) & 3, ent & 7);
    }
}

// ---- monolithic fallback (no workspace dependence) ----
__global__ __launch_bounds__(512) void attn_fwd_mono(
    const float* __restrict__ Q,
    const float* __restrict__ K,
    const float* __restrict__ V,
    const int*   __restrict__ cu,
    float*       __restrict__ O)
{
    __shared__ __align__(16) unsigned char smem[58368];
    attn_tile_body<false>(Q, K, V, nullptr, nullptr, cu, O, nullptr, smem,
                          (int)gridDim.x - 1 - (int)blockIdx.x,
                          (int)blockIdx.y, 0);
}

// Combine up to 8 chunk partials per (tile, g). bf16 O partials, f32
// accumulate, online merge. Only multi-chunk tiles (fwd stored O direct
// for nc_eff==1). Kernel-boundary ordering makes partials visible (G16).
__global__ __launch_bounds__(256) void attn_merge(
    const int*   __restrict__ cu,
    const float* __restrict__ WS,
    float*       __restrict__ O)
{
    const int tile  = blockIdx.x;
    const int g     = blockIdx.y;
    const int qbase = tile * 32;
    int seg0 = 0;
    #pragma unroll
    for (int j = 1; j < NCU; ++j) { int cj = cu[j]; if (cj <= qbase) seg0 = cj; }
    const int k0       = seg0 & ~31;
    const int nblk_tot = (qbase + 32 - k0) >> 5;
    int chunk, nc; chunk_geom(nblk_tot, chunk, nc);
    if (nc <= 1) return;

    const int tid  = threadIdx.x;
    const int row  = tid >> 1;           // hw*32 + q  (128 rows)
    const int half = tid & 1;            // which 64-elem half of D
    const int hw   = row >> 5;
    const int q    = row & 31;

    float m = -30000.0f, l = 0.0f;
    float4_t acc[16];
    #pragma unroll
    for (int i = 0; i < 16; ++i) acc[i] = (float4_t){0.f, 0.f, 0.f, 0.f};

    const long sbase = ((long)(tile * 4 + g)) * 8;
    for (int c = 0; c < nc; ++c) {
        const float* mlp = WS + ML_OFF + (sbase + c) * 256 + row * 2;
        const float mc = mlp[0], lc = mlp[1];
        const float mn = fmaxf(m, mc);
        const float a0 = __builtin_exp2f(m - mn);
        const float a1 = __builtin_exp2f(mc - mn);
        l = l * a0 + lc * a1;
        const ushort* op = (const ushort*)WS + (sbase + c) * 16384 + row * 128 + half * 64;
        #pragma unroll
        for (int i = 0; i < 8; ++i) {
            short8_t v8 = *(const short8_t*)(op + i * 8);
            float4_t lo, hi;
            lo[0] = bf2f((ushort)v8[0]); lo[1] = bf2f((ushort)v8[1]);
            lo[2] = bf2f((ushort)v8[2]); lo[3] = bf2f((ushort)v8[3]);
            hi[0] = bf2f((ushort)v8[4]); hi[1] = bf2f((ushort)v8[5]);
            hi[2] = bf2f((ushort)v8[6]); hi[3] = bf2f((ushort)v8[7]);
            acc[2 * i]     = acc[2 * i] * a0 + lo * a1;
            acc[2 * i + 1] = acc[2 * i + 1] * a0 + hi * a1;
        }
        m = mn;
    }
    const float inv = 1.0f / l;
    float* o = O + ((long)(qbase + q) * NH + g * 4 + hw) * HD + half * 64;
    #pragma unroll
    for (int i = 0; i < 16; ++i)
        *(float4_t*)(o + i * 4) = acc[i] * inv;
}

extern "C" void kernel_launch(void* const* d_in, const int* in_sizes, int n_in,
                              void* d_out, int out_size, void* d_ws, size_t ws_size,
                              hipStream_t stream) {
    const float* Q  = (const float*)d_in[0];
    const float* K  = (const float*)d_in[1];
    const float* V  = (const float*)d_in[2];
    const int*   cu = (const int*)d_in[3];
    float*       O  = (float*)d_out;
    const size_t need = (size_t)WS_END * sizeof(float);   // 146.8 MB
    if (d_ws != nullptr && ws_size >= need) {
        float* WS = (float*)d_ws;
        prep_all<<<1537, 256, 0, stream>>>(K, V, cu, WS);
        attn_fwd_persist<<<512, 512, 0, stream>>>(Q, K, V, cu, O, WS);
        attn_merge<<<dim3(T_TOK / 32, NG), 256, 0, stream>>>(
            cu, (const float*)WS, O);
    } else {
        attn_fwd_mono<<<dim3(T_TOK / 32, NG), 512, 0, stream>>>(Q, K, V, cu, O);
    }
}